// Round 2
// 97.998 us; speedup vs baseline: 1.0134x; 1.0134x over previous
//
#include <hip/hip_runtime.h>
#include <stdint.h>

#define NTREES 8
#define NNODES 5
#define CC 16
#define BB 8
#define HH 224
#define WW 224
#define NBAND 28          // 224 / 8 rows per band (even -> 2-band ping-pong)

struct Forest { int par[NTREES * NNODES]; };
struct Cls { int v[NTREES]; };

// ---------------------------------------------------------------------------
// Host-side bit-exact reproduction of np.random.default_rng(0) forest
// (verified absmax 0.0 vs numpy in rounds 1-10 — do not touch).
// ---------------------------------------------------------------------------
namespace nprng {

struct Pcg {
  __uint128_t state, inc;
  int has_uint32;
  uint32_t uinteger;
};

static inline __uint128_t pcg_mult() {
  return (((__uint128_t)0x2360ED051FC65DA4ULL) << 64) | 0x4385DF649FCCF645ULL;
}

static inline void pcg_step(Pcg& s) { s.state = s.state * pcg_mult() + s.inc; }

static inline uint64_t pcg_next64(Pcg& s) {
  pcg_step(s);
  uint64_t xored = (uint64_t)(s.state >> 64) ^ (uint64_t)s.state;
  unsigned rot = (unsigned)(s.state >> 122);
  return (xored >> rot) | (xored << ((64u - rot) & 63u));
}

static inline uint32_t pcg_next32(Pcg& s) {
  if (s.has_uint32) { s.has_uint32 = 0; return s.uinteger; }
  uint64_t n = pcg_next64(s);
  s.has_uint32 = 1;
  s.uinteger = (uint32_t)(n >> 32);
  return (uint32_t)n;
}

static inline uint32_t lemire32(Pcg& s, uint32_t rng) {
  const uint32_t rng_excl = rng + 1u;
  uint64_t m = (uint64_t)pcg_next32(s) * (uint64_t)rng_excl;
  uint32_t leftover = (uint32_t)m;
  if (leftover < rng_excl) {
    const uint32_t threshold = (uint32_t)((0xFFFFFFFFu - rng) % rng_excl);
    while (leftover < threshold) {
      m = (uint64_t)pcg_next32(s) * (uint64_t)rng_excl;
      leftover = (uint32_t)m;
    }
  }
  return (uint32_t)(m >> 32);
}

static void make_forest(Forest& f) {
  const uint32_t INIT_A = 0x43b0d7e5u, MULT_A = 0x931e8875u;
  const uint32_t INIT_B = 0x8b51f9ddu, MULT_B = 0x58f38dedu;
  const uint32_t MIX_L  = 0xca01f9ddu, MIX_R  = 0x4973f715u;
  uint32_t pool[4];
  uint32_t hc = INIT_A;
  auto hashmix = [&](uint32_t v) -> uint32_t {
    v ^= hc; hc *= MULT_A; v *= hc; v ^= v >> 16; return v;
  };
  auto mix = [&](uint32_t x, uint32_t y) -> uint32_t {
    uint32_t r = MIX_L * x - MIX_R * y; r ^= r >> 16; return r;
  };
  pool[0] = hashmix(0u);
  for (int i = 1; i < 4; ++i) pool[i] = hashmix(0u);
  for (int is = 0; is < 4; ++is)
    for (int id = 0; id < 4; ++id)
      if (is != id) pool[id] = mix(pool[id], hashmix(pool[is]));
  uint32_t st32[8];
  uint32_t hb = INIT_B;
  for (int i = 0; i < 8; ++i) {
    uint32_t dv = pool[i & 3];
    dv ^= hb; hb *= MULT_B; dv *= hb; dv ^= dv >> 16;
    st32[i] = dv;
  }
  uint64_t w64[4];
  for (int i = 0; i < 4; ++i)
    w64[i] = (uint64_t)st32[2 * i] | ((uint64_t)st32[2 * i + 1] << 32);

  __uint128_t initstate = (((__uint128_t)w64[0]) << 64) | w64[1];
  __uint128_t initseq   = (((__uint128_t)w64[2]) << 64) | w64[3];
  Pcg s;
  s.state = 0; s.inc = (initseq << 1) | 1;
  pcg_step(s);
  s.state += initstate;
  pcg_step(s);
  s.has_uint32 = 0; s.uinteger = 0;

  for (int t = 0; t < NTREES; ++t) {
    f.par[t * NNODES + 0] = -1;
    for (int i = 1; i < NNODES; ++i) {
      uint32_t rng = (uint32_t)(i - 1);
      f.par[t * NNODES + i] = (rng == 0) ? 0 : (int)lemire32(s, rng);
    }
  }
}

}  // namespace nprng

// ---------------------------------------------------------------------------
// Tree-shape classification + level-form class configs (verified absmax 0.0
// in R8/R10): chain C1 = fv*sL^E1L; C2 = fv*sL^E2L*sC1; C3 = fv*sC2;
// root = fv*sL^RL*sC1^R1*sC2^R2*sC3^R3.
// ---------------------------------------------------------------------------
static int classify_tree(const int* p) {
  int nch[NNODES] = {0, 0, 0, 0, 0};
  for (int i = 1; i < NNODES; ++i) nch[p[i]]++;
  int internals[3], nI = 0;
  for (int i = 1; i <= 3; ++i) if (nch[i] > 0) internals[nI++] = i;
  if (nI == 0) return 1;
  if (nI == 1) {
    int m = nch[internals[0]];
    return m == 1 ? 2 : (m == 2 ? 3 : 4);
  }
  if (nI == 2) {
    int i = internals[0], j = internals[1];
    if (p[j] == i) {
      if (nch[j] == 2) return 9;
      return (nch[i] - 1 == 1) ? 7 : 6;
    }
    return 5;
  }
  return 8;
}

template <int CL> struct TC;
template <> struct TC<1> { static constexpr int H1=0,E1L=0,H2=0,E2L=0,H3=0,RL=4,R1=0,R2=0,R3=0; };
template <> struct TC<2> { static constexpr int H1=1,E1L=1,H2=0,E2L=0,H3=0,RL=2,R1=1,R2=0,R3=0; };
template <> struct TC<3> { static constexpr int H1=1,E1L=2,H2=0,E2L=0,H3=0,RL=1,R1=1,R2=0,R3=0; };
template <> struct TC<4> { static constexpr int H1=1,E1L=3,H2=0,E2L=0,H3=0,RL=0,R1=1,R2=0,R3=0; };
template <> struct TC<5> { static constexpr int H1=1,E1L=1,H2=0,E2L=0,H3=0,RL=0,R1=2,R2=0,R3=0; };
template <> struct TC<6> { static constexpr int H1=1,E1L=1,H2=1,E2L=0,H3=0,RL=1,R1=0,R2=1,R3=0; };
template <> struct TC<7> { static constexpr int H1=1,E1L=1,H2=1,E2L=1,H3=0,RL=0,R1=0,R2=1,R3=0; };
template <> struct TC<8> { static constexpr int H1=1,E1L=1,H2=1,E2L=0,H3=1,RL=0,R1=0,R2=0,R3=1; };
template <> struct TC<9> { static constexpr int H1=1,E1L=2,H2=1,E2L=0,H3=0,RL=0,R1=0,R2=1,R3=0; };

// ---------------------------------------------------------------------------
// DPP helpers (product space, max identity 0.0; patterns verified R4-R10).
// wshr1: single v_mov_b32_dpp wave_shr:1, 0 into lane 0 (border sentinel).
// SCAN8: 8 INDEPENDENT inclusive 64-lane max-scans, stage-major interleaved
// (dependent same-register DPPs are 8 insts apart -> no internal nops).
// Leading/trailing s_nop 1 cover VALU<->DPP hazards at the asm boundary.
// ---------------------------------------------------------------------------
__device__ __forceinline__ float wshr1(float t) {
  int r = __builtin_amdgcn_update_dpp(
      0, __builtin_bit_cast(int, t), 0x138, 0xf, 0xf, true);  // wave_shr:1
  return __builtin_bit_cast(float, r);
}

#define S8STAGE(MODS) \
  "v_max_f32_dpp %0, %0, %0 " MODS "\n\t" \
  "v_max_f32_dpp %1, %1, %1 " MODS "\n\t" \
  "v_max_f32_dpp %2, %2, %2 " MODS "\n\t" \
  "v_max_f32_dpp %3, %3, %3 " MODS "\n\t" \
  "v_max_f32_dpp %4, %4, %4 " MODS "\n\t" \
  "v_max_f32_dpp %5, %5, %5 " MODS "\n\t" \
  "v_max_f32_dpp %6, %6, %6 " MODS "\n\t" \
  "v_max_f32_dpp %7, %7, %7 " MODS "\n\t"

#define SCAN8(q)                                              \
  asm volatile(                                               \
      "s_nop 1\n\t"                                           \
      S8STAGE("row_shr:1 row_mask:0xf bank_mask:0xf")         \
      S8STAGE("row_shr:2 row_mask:0xf bank_mask:0xf")         \
      S8STAGE("row_shr:4 row_mask:0xf bank_mask:0xf")         \
      S8STAGE("row_shr:8 row_mask:0xf bank_mask:0xf")         \
      S8STAGE("row_bcast:15 row_mask:0xa bank_mask:0xf")      \
      S8STAGE("row_bcast:31 row_mask:0xc bank_mask:0xf")      \
      "s_nop 1"                                               \
      : "+v"(q[0]), "+v"(q[1]), "+v"(q[2]), "+v"(q[3]),       \
        "+v"(q[4]), "+v"(q[5]), "+v"(q[6]), "+v"(q[7]))

#define MUL4(d, s) { (d).x *= (s).x; (d).y *= (s).y; (d).z *= (s).z; (d).w *= (s).w; }
#define MAX4(d, s) { (d).x = fmaxf((d).x,(s).x); (d).y = fmaxf((d).y,(s).y); \
                     (d).z = fmaxf((d).z,(s).z); (d).w = fmaxf((d).w,(s).w); }

template <int E>
__device__ __forceinline__ void powmul(float4& v, const float4& s) {
  if constexpr (E == 4) {
    float4 t = s; MUL4(t, t); MUL4(t, t); MUL4(v, t);
  } else {
    if constexpr (E >= 1) MUL4(v, s);
    if constexpr (E >= 2) MUL4(v, s);
    if constexpr (E >= 3) MUL4(v, s);
  }
}

// s(h) = shift of M(h-1): row -1 comes from the band carry.
__device__ __forceinline__ float4 shiftrow(const float4* M, int u, const float4& carry) {
  float4 p = (u == 0) ? carry : M[u - 1];
  return make_float4(wshr1(p.w), p.x, p.y, p.z);
}

// ---------------------------------------------------------------------------
// One band of the level-pass DP. X = this band's 8 preloaded rows; T is the
// OTHER register bank, into which the NEXT band's rows are prefetched (the
// caller ping-pongs XA/XB, eliminating the 32 v_mov/band register copy of
// the previous revision). All arithmetic (op order, DPP patterns,
// carry-after-use ordering) is identical to the verified R8/R10 structure.
// ---------------------------------------------------------------------------
template <int CL>
__device__ __forceinline__ void band_pass(const float* __restrict__ cp, int band,
                                          float mask,
                                          float4 (&X)[8], float4 (&T)[8],
                                          float4& cL, float4& c1, float4& c2,
                                          float4& c3, float4& racc) {
  using F = TC<CL>;

  // prefetch next band into the other bank (band 27 reloads itself, unused)
  const int nb = (band + 1 < NBAND) ? band + 1 : NBAND - 1;
  const float* __restrict__ tp = cp + (size_t)(nb * 8) * WW;
#pragma unroll
  for (int u = 0; u < 8; ++u)
    T[u] = *(const float4*)(tp + u * WW);

  float4 fv[8];
#pragma unroll
  for (int u = 0; u < 8; ++u) {
    const float4 xr = X[u];
    fv[u].x = fmaf(fmaxf(xr.x, 0.f), mask, mask);
    fv[u].y = fmaf(fmaxf(xr.y, 0.f), mask, mask);
    fv[u].z = fmaf(fmaxf(xr.z, 0.f), mask, mask);
    fv[u].w = fmaf(fmaxf(xr.w, 0.f), mask, mask);
  }

  float4 ML[8], M1[8], M2[8], M3[8];

  // ---- pass 0: leaf chain (v = fv) ----
  {
    float l0[8], l1[8], l2[8], q[8];
#pragma unroll
    for (int u = 0; u < 8; ++u) {
      l0[u] = fv[u].x;
      l1[u] = fmaxf(l0[u], fv[u].y);
      l2[u] = fmaxf(l1[u], fv[u].z);
      q[u]  = fmaxf(l2[u], fv[u].w);
    }
    SCAN8(q);
    float4 run = cL;
#pragma unroll
    for (int u = 0; u < 8; ++u) {
      float e = wshr1(q[u]);
      run.x = fmaxf(run.x, fmaxf(e, l0[u]));
      run.y = fmaxf(run.y, fmaxf(e, l1[u]));
      run.z = fmaxf(run.z, fmaxf(e, l2[u]));
      run.w = fmaxf(run.w, q[u]);
      ML[u] = run;
    }
  }

  // ---- pass 1: C1 = fv * sL^E1L ----
  if constexpr (F::H1) {
    float l0[8], l1[8], l2[8], q[8];
#pragma unroll
    for (int u = 0; u < 8; ++u) {
      float4 v = fv[u];
      powmul<F::E1L>(v, shiftrow(ML, u, cL));
      l0[u] = v.x;
      l1[u] = fmaxf(l0[u], v.y);
      l2[u] = fmaxf(l1[u], v.z);
      q[u]  = fmaxf(l2[u], v.w);
    }
    SCAN8(q);
    float4 run = c1;
#pragma unroll
    for (int u = 0; u < 8; ++u) {
      float e = wshr1(q[u]);
      run.x = fmaxf(run.x, fmaxf(e, l0[u]));
      run.y = fmaxf(run.y, fmaxf(e, l1[u]));
      run.z = fmaxf(run.z, fmaxf(e, l2[u]));
      run.w = fmaxf(run.w, q[u]);
      M1[u] = run;
    }
  }

  // ---- pass 2: C2 = fv * sL^E2L * sC1 ----
  if constexpr (F::H2) {
    float l0[8], l1[8], l2[8], q[8];
#pragma unroll
    for (int u = 0; u < 8; ++u) {
      float4 v = fv[u];
      if constexpr (F::E2L > 0) powmul<F::E2L>(v, shiftrow(ML, u, cL));
      { float4 s1 = shiftrow(M1, u, c1); MUL4(v, s1); }
      l0[u] = v.x;
      l1[u] = fmaxf(l0[u], v.y);
      l2[u] = fmaxf(l1[u], v.z);
      q[u]  = fmaxf(l2[u], v.w);
    }
    SCAN8(q);
    float4 run = c2;
#pragma unroll
    for (int u = 0; u < 8; ++u) {
      float e = wshr1(q[u]);
      run.x = fmaxf(run.x, fmaxf(e, l0[u]));
      run.y = fmaxf(run.y, fmaxf(e, l1[u]));
      run.z = fmaxf(run.z, fmaxf(e, l2[u]));
      run.w = fmaxf(run.w, q[u]);
      M2[u] = run;
    }
  }

  // ---- pass 3: C3 = fv * sC2 ----
  if constexpr (F::H3) {
    float l0[8], l1[8], l2[8], q[8];
#pragma unroll
    for (int u = 0; u < 8; ++u) {
      float4 v = fv[u];
      { float4 s2 = shiftrow(M2, u, c2); MUL4(v, s2); }
      l0[u] = v.x;
      l1[u] = fmaxf(l0[u], v.y);
      l2[u] = fmaxf(l1[u], v.z);
      q[u]  = fmaxf(l2[u], v.w);
    }
    SCAN8(q);
    float4 run = c3;
#pragma unroll
    for (int u = 0; u < 8; ++u) {
      float e = wshr1(q[u]);
      run.x = fmaxf(run.x, fmaxf(e, l0[u]));
      run.y = fmaxf(run.y, fmaxf(e, l1[u]));
      run.z = fmaxf(run.z, fmaxf(e, l2[u]));
      run.w = fmaxf(run.w, q[u]);
      M3[u] = run;
    }
  }

  // ---- root pass: r(h) = fv * sL^RL * sC1^R1 * sC2^R2 * sC3^R3 ----
#pragma unroll
  for (int u = 0; u < 8; ++u) {
    float4 r = fv[u];
    if constexpr (F::RL > 0) powmul<F::RL>(r, shiftrow(ML, u, cL));
    if constexpr (F::R1 > 0) powmul<F::R1>(r, shiftrow(M1, u, c1));
    if constexpr (F::R2 > 0) powmul<F::R2>(r, shiftrow(M2, u, c2));
    if constexpr (F::R3 > 0) powmul<F::R3>(r, shiftrow(M3, u, c3));
    MAX4(racc, r);
  }

  // band carries (updated only after all uses of the old values)
  cL = ML[7];
  if constexpr (F::H1) c1 = M1[7];
  if constexpr (F::H2) c2 = M2[7];
  if constexpr (F::H3) c3 = M3[7];
}

// ---------------------------------------------------------------------------
// Band-parallel level-pass DP. One wave per (tree,b,c). Product space
// (exp isomorphism, verified R6-R10): f=(1+relu(x))*mask, sentinel 0.0,
// out = exp(asum)*m - 1.  Bands are processed in ping-pong pairs (NBAND
// even): band 2k computes from XA while prefetching into XB, band 2k+1 the
// reverse — no register-bank copy at band end.
// ---------------------------------------------------------------------------
template <int CL>
__device__ __forceinline__ void run_tree(const float* __restrict__ cp,
                                         float mask, float asum,
                                         float* __restrict__ outp, int lane) {
  const float4 z4 = make_float4(0.f, 0.f, 0.f, 0.f);
  float4 cL = z4, c1 = z4, c2 = z4, c3 = z4, racc = z4;

  float4 XA[8], XB[8];
#pragma unroll
  for (int u = 0; u < 8; ++u) XA[u] = *(const float4*)(cp + u * WW);

#pragma unroll 1
  for (int it = 0; it < NBAND; it += 2) {
    band_pass<CL>(cp, it,     mask, XA, XB, cL, c1, c2, c3, racc);
    band_pass<CL>(cp, it + 1, mask, XB, XA, cL, c1, c2, c3, racc);
  }

  float m = fmaxf(fmaxf(racc.x, racc.y), fmaxf(racc.z, racc.w));
#pragma unroll
  for (int d = 1; d < 64; d <<= 1) m = fmaxf(m, __shfl_xor(m, d));
  if (lane == 0) *outp = expf(asum) * m - 1.f;
}

__global__ __launch_bounds__(64) void fis_kernel(const float* __restrict__ x,
                                                 const float* __restrict__ alphas,
                                                 float* __restrict__ out,
                                                 Cls cls) {
  const int lane = threadIdx.x;
  const int blk  = blockIdx.x;
  const int t    = blk >> 7;     // blocks 128 apart share x-plane -> same XCD
  const int bc   = blk & 127;
  const int c    = bc & (CC - 1);
  const int b    = bc >> 4;

  const float* __restrict__ xp = x + (size_t)bc * (HH * WW);

  float asum = 0.f;
#pragma unroll
  for (int i = 0; i < NNODES; ++i) asum += alphas[(t * NNODES + i) * CC + c];

  const int   w0   = lane * 4;
  const float mask = (w0 < WW) ? 1.0f : 0.0f;
  const float* __restrict__ cp = xp + ((w0 < WW) ? w0 : (WW - 4));
  float* outp = out + ((size_t)b * NTREES + t) * CC + c;

  switch (cls.v[t]) {
    case 1: run_tree<1>(cp, mask, asum, outp, lane); break;
    case 2: run_tree<2>(cp, mask, asum, outp, lane); break;
    case 3: run_tree<3>(cp, mask, asum, outp, lane); break;
    case 4: run_tree<4>(cp, mask, asum, outp, lane); break;
    case 5: run_tree<5>(cp, mask, asum, outp, lane); break;
    case 6: run_tree<6>(cp, mask, asum, outp, lane); break;
    case 7: run_tree<7>(cp, mask, asum, outp, lane); break;
    case 8: run_tree<8>(cp, mask, asum, outp, lane); break;
    case 9: run_tree<9>(cp, mask, asum, outp, lane); break;
    default: break;
  }
}

extern "C" void kernel_launch(void* const* d_in, const int* in_sizes, int n_in,
                              void* d_out, int out_size, void* d_ws, size_t ws_size,
                              hipStream_t stream) {
  const float* x      = (const float*)d_in[0];
  const float* alphas = (const float*)d_in[1];
  float* out          = (float*)d_out;

  Forest f;
  nprng::make_forest(f);  // deterministic; same every call (graph-capture safe)

  Cls cls;
  for (int t = 0; t < NTREES; ++t)
    cls.v[t] = classify_tree(&f.par[t * NNODES]);

  dim3 grid(BB * CC * NTREES);  // 1024 single-wave blocks
  dim3 block(64);
  hipLaunchKernelGGL(fis_kernel, grid, block, 0, stream, x, alphas, out, cls);
}

// Round 3
// 97.254 us; speedup vs baseline: 1.0212x; 1.0077x over previous
//
#include <hip/hip_runtime.h>
#include <stdint.h>

#define NTREES 8
#define NNODES 5
#define CC 16
#define BB 8
#define HH 224
#define WW 224
#define NBAND 28          // 224 / 8 rows per band (even -> 2-band ping-pong)

struct Forest { int par[NTREES * NNODES]; };
struct Cls { int v[NTREES]; };

// ---------------------------------------------------------------------------
// Host-side bit-exact reproduction of np.random.default_rng(0) forest
// (verified absmax 0.0 vs numpy in rounds 1-10 — do not touch).
// ---------------------------------------------------------------------------
namespace nprng {

struct Pcg {
  __uint128_t state, inc;
  int has_uint32;
  uint32_t uinteger;
};

static inline __uint128_t pcg_mult() {
  return (((__uint128_t)0x2360ED051FC65DA4ULL) << 64) | 0x4385DF649FCCF645ULL;
}

static inline void pcg_step(Pcg& s) { s.state = s.state * pcg_mult() + s.inc; }

static inline uint64_t pcg_next64(Pcg& s) {
  pcg_step(s);
  uint64_t xored = (uint64_t)(s.state >> 64) ^ (uint64_t)s.state;
  unsigned rot = (unsigned)(s.state >> 122);
  return (xored >> rot) | (xored << ((64u - rot) & 63u));
}

static inline uint32_t pcg_next32(Pcg& s) {
  if (s.has_uint32) { s.has_uint32 = 0; return s.uinteger; }
  uint64_t n = pcg_next64(s);
  s.has_uint32 = 1;
  s.uinteger = (uint32_t)(n >> 32);
  return (uint32_t)n;
}

static inline uint32_t lemire32(Pcg& s, uint32_t rng) {
  const uint32_t rng_excl = rng + 1u;
  uint64_t m = (uint64_t)pcg_next32(s) * (uint64_t)rng_excl;
  uint32_t leftover = (uint32_t)m;
  if (leftover < rng_excl) {
    const uint32_t threshold = (uint32_t)((0xFFFFFFFFu - rng) % rng_excl);
    while (leftover < threshold) {
      m = (uint64_t)pcg_next32(s) * (uint64_t)rng_excl;
      leftover = (uint32_t)m;
    }
  }
  return (uint32_t)(m >> 32);
}

static void make_forest(Forest& f) {
  const uint32_t INIT_A = 0x43b0d7e5u, MULT_A = 0x931e8875u;
  const uint32_t INIT_B = 0x8b51f9ddu, MULT_B = 0x58f38dedu;
  const uint32_t MIX_L  = 0xca01f9ddu, MIX_R  = 0x4973f715u;
  uint32_t pool[4];
  uint32_t hc = INIT_A;
  auto hashmix = [&](uint32_t v) -> uint32_t {
    v ^= hc; hc *= MULT_A; v *= hc; v ^= v >> 16; return v;
  };
  auto mix = [&](uint32_t x, uint32_t y) -> uint32_t {
    uint32_t r = MIX_L * x - MIX_R * y; r ^= r >> 16; return r;
  };
  pool[0] = hashmix(0u);
  for (int i = 1; i < 4; ++i) pool[i] = hashmix(0u);
  for (int is = 0; is < 4; ++is)
    for (int id = 0; id < 4; ++id)
      if (is != id) pool[id] = mix(pool[id], hashmix(pool[is]));
  uint32_t st32[8];
  uint32_t hb = INIT_B;
  for (int i = 0; i < 8; ++i) {
    uint32_t dv = pool[i & 3];
    dv ^= hb; hb *= MULT_B; dv *= hb; dv ^= dv >> 16;
    st32[i] = dv;
  }
  uint64_t w64[4];
  for (int i = 0; i < 4; ++i)
    w64[i] = (uint64_t)st32[2 * i] | ((uint64_t)st32[2 * i + 1] << 32);

  __uint128_t initstate = (((__uint128_t)w64[0]) << 64) | w64[1];
  __uint128_t initseq   = (((__uint128_t)w64[2]) << 64) | w64[3];
  Pcg s;
  s.state = 0; s.inc = (initseq << 1) | 1;
  pcg_step(s);
  s.state += initstate;
  pcg_step(s);
  s.has_uint32 = 0; s.uinteger = 0;

  for (int t = 0; t < NTREES; ++t) {
    f.par[t * NNODES + 0] = -1;
    for (int i = 1; i < NNODES; ++i) {
      uint32_t rng = (uint32_t)(i - 1);
      f.par[t * NNODES + i] = (rng == 0) ? 0 : (int)lemire32(s, rng);
    }
  }
}

}  // namespace nprng

// ---------------------------------------------------------------------------
// Tree-shape classification + level-form class configs (verified absmax 0.0
// in R8/R10): chain C1 = fv*sL^E1L; C2 = fv*sL^E2L*sC1; C3 = fv*sC2;
// root = fv*sL^RL*sC1^R1*sC2^R2*sC3^R3.
// ---------------------------------------------------------------------------
static int classify_tree(const int* p) {
  int nch[NNODES] = {0, 0, 0, 0, 0};
  for (int i = 1; i < NNODES; ++i) nch[p[i]]++;
  int internals[3], nI = 0;
  for (int i = 1; i <= 3; ++i) if (nch[i] > 0) internals[nI++] = i;
  if (nI == 0) return 1;
  if (nI == 1) {
    int m = nch[internals[0]];
    return m == 1 ? 2 : (m == 2 ? 3 : 4);
  }
  if (nI == 2) {
    int i = internals[0], j = internals[1];
    if (p[j] == i) {
      if (nch[j] == 2) return 9;
      return (nch[i] - 1 == 1) ? 7 : 6;
    }
    return 5;
  }
  return 8;
}

template <int CL> struct TC;
template <> struct TC<1> { static constexpr int H1=0,E1L=0,H2=0,E2L=0,H3=0,RL=4,R1=0,R2=0,R3=0; };
template <> struct TC<2> { static constexpr int H1=1,E1L=1,H2=0,E2L=0,H3=0,RL=2,R1=1,R2=0,R3=0; };
template <> struct TC<3> { static constexpr int H1=1,E1L=2,H2=0,E2L=0,H3=0,RL=1,R1=1,R2=0,R3=0; };
template <> struct TC<4> { static constexpr int H1=1,E1L=3,H2=0,E2L=0,H3=0,RL=0,R1=1,R2=0,R3=0; };
template <> struct TC<5> { static constexpr int H1=1,E1L=1,H2=0,E2L=0,H3=0,RL=0,R1=2,R2=0,R3=0; };
template <> struct TC<6> { static constexpr int H1=1,E1L=1,H2=1,E2L=0,H3=0,RL=1,R1=0,R2=1,R3=0; };
template <> struct TC<7> { static constexpr int H1=1,E1L=1,H2=1,E2L=1,H3=0,RL=0,R1=0,R2=1,R3=0; };
template <> struct TC<8> { static constexpr int H1=1,E1L=1,H2=1,E2L=0,H3=1,RL=0,R1=0,R2=0,R3=1; };
template <> struct TC<9> { static constexpr int H1=1,E1L=2,H2=1,E2L=0,H3=0,RL=0,R1=0,R2=1,R3=0; };

// ---------------------------------------------------------------------------
// DPP helpers (product space, max identity 0.0; patterns verified R4-R10).
// wshr1: single v_mov_b32_dpp wave_shr:1, 0 into lane 0 (border sentinel).
// SCAN8: 8 INDEPENDENT inclusive 64-lane max-scans, stage-major interleaved
// (dependent same-register DPPs are 8 insts apart -> no internal nops).
// Leading/trailing s_nop 1 cover VALU<->DPP hazards at the asm boundary.
// ---------------------------------------------------------------------------
__device__ __forceinline__ float wshr1(float t) {
  int r = __builtin_amdgcn_update_dpp(
      0, __builtin_bit_cast(int, t), 0x138, 0xf, 0xf, true);  // wave_shr:1
  return __builtin_bit_cast(float, r);
}

#define S8STAGE(MODS) \
  "v_max_f32_dpp %0, %0, %0 " MODS "\n\t" \
  "v_max_f32_dpp %1, %1, %1 " MODS "\n\t" \
  "v_max_f32_dpp %2, %2, %2 " MODS "\n\t" \
  "v_max_f32_dpp %3, %3, %3 " MODS "\n\t" \
  "v_max_f32_dpp %4, %4, %4 " MODS "\n\t" \
  "v_max_f32_dpp %5, %5, %5 " MODS "\n\t" \
  "v_max_f32_dpp %6, %6, %6 " MODS "\n\t" \
  "v_max_f32_dpp %7, %7, %7 " MODS "\n\t"

#define SCAN8(q)                                              \
  asm volatile(                                               \
      "s_nop 1\n\t"                                           \
      S8STAGE("row_shr:1 row_mask:0xf bank_mask:0xf")         \
      S8STAGE("row_shr:2 row_mask:0xf bank_mask:0xf")         \
      S8STAGE("row_shr:4 row_mask:0xf bank_mask:0xf")         \
      S8STAGE("row_shr:8 row_mask:0xf bank_mask:0xf")         \
      S8STAGE("row_bcast:15 row_mask:0xa bank_mask:0xf")      \
      S8STAGE("row_bcast:31 row_mask:0xc bank_mask:0xf")      \
      "s_nop 1"                                               \
      : "+v"(q[0]), "+v"(q[1]), "+v"(q[2]), "+v"(q[3]),       \
        "+v"(q[4]), "+v"(q[5]), "+v"(q[6]), "+v"(q[7]))

#define MUL4(d, s) { (d).x *= (s).x; (d).y *= (s).y; (d).z *= (s).z; (d).w *= (s).w; }
#define MAX4(d, s) { (d).x = fmaxf((d).x,(s).x); (d).y = fmaxf((d).y,(s).y); \
                     (d).z = fmaxf((d).z,(s).z); (d).w = fmaxf((d).w,(s).w); }

template <int E>
__device__ __forceinline__ void powmul(float4& v, const float4& s) {
  if constexpr (E == 4) {
    float4 t = s; MUL4(t, t); MUL4(t, t); MUL4(v, t);
  } else {
    if constexpr (E >= 1) MUL4(v, s);
    if constexpr (E >= 2) MUL4(v, s);
    if constexpr (E >= 3) MUL4(v, s);
  }
}

// s(h) = shift of M(h-1): row -1 comes from the band carry.
__device__ __forceinline__ float4 shiftrow(const float4* M, int u, const float4& carry) {
  float4 p = (u == 0) ? carry : M[u - 1];
  return make_float4(wshr1(p.w), p.x, p.y, p.z);
}

// ---------------------------------------------------------------------------
// One band of the level-pass DP. X = this band's 8 preloaded rows; T is the
// OTHER register bank, into which the NEXT band's rows are prefetched (the
// caller ping-pongs XA/XB). All arithmetic (op order, DPP patterns,
// carry-after-use ordering) is identical to the verified R8/R10 structure.
// ---------------------------------------------------------------------------
template <int CL>
__device__ __forceinline__ void band_pass(const float* __restrict__ cp, int band,
                                          float mask,
                                          float4 (&X)[8], float4 (&T)[8],
                                          float4& cL, float4& c1, float4& c2,
                                          float4& c3, float4& racc) {
  using F = TC<CL>;

  // prefetch next band into the other bank (band 27 reloads itself, unused)
  const int nb = (band + 1 < NBAND) ? band + 1 : NBAND - 1;
  const float* __restrict__ tp = cp + (size_t)(nb * 8) * WW;
#pragma unroll
  for (int u = 0; u < 8; ++u)
    T[u] = *(const float4*)(tp + u * WW);

  float4 fv[8];
#pragma unroll
  for (int u = 0; u < 8; ++u) {
    const float4 xr = X[u];
    fv[u].x = fmaf(fmaxf(xr.x, 0.f), mask, mask);
    fv[u].y = fmaf(fmaxf(xr.y, 0.f), mask, mask);
    fv[u].z = fmaf(fmaxf(xr.z, 0.f), mask, mask);
    fv[u].w = fmaf(fmaxf(xr.w, 0.f), mask, mask);
  }

  float4 ML[8], M1[8], M2[8], M3[8];

  // ---- pass 0: leaf chain (v = fv) ----
  {
    float l0[8], l1[8], l2[8], q[8];
#pragma unroll
    for (int u = 0; u < 8; ++u) {
      l0[u] = fv[u].x;
      l1[u] = fmaxf(l0[u], fv[u].y);
      l2[u] = fmaxf(l1[u], fv[u].z);
      q[u]  = fmaxf(l2[u], fv[u].w);
    }
    SCAN8(q);
    float4 run = cL;
#pragma unroll
    for (int u = 0; u < 8; ++u) {
      float e = wshr1(q[u]);
      run.x = fmaxf(run.x, fmaxf(e, l0[u]));
      run.y = fmaxf(run.y, fmaxf(e, l1[u]));
      run.z = fmaxf(run.z, fmaxf(e, l2[u]));
      run.w = fmaxf(run.w, q[u]);
      ML[u] = run;
    }
  }

  // ---- pass 1: C1 = fv * sL^E1L ----
  if constexpr (F::H1) {
    float l0[8], l1[8], l2[8], q[8];
#pragma unroll
    for (int u = 0; u < 8; ++u) {
      float4 v = fv[u];
      powmul<F::E1L>(v, shiftrow(ML, u, cL));
      l0[u] = v.x;
      l1[u] = fmaxf(l0[u], v.y);
      l2[u] = fmaxf(l1[u], v.z);
      q[u]  = fmaxf(l2[u], v.w);
    }
    SCAN8(q);
    float4 run = c1;
#pragma unroll
    for (int u = 0; u < 8; ++u) {
      float e = wshr1(q[u]);
      run.x = fmaxf(run.x, fmaxf(e, l0[u]));
      run.y = fmaxf(run.y, fmaxf(e, l1[u]));
      run.z = fmaxf(run.z, fmaxf(e, l2[u]));
      run.w = fmaxf(run.w, q[u]);
      M1[u] = run;
    }
  }

  // ---- pass 2: C2 = fv * sL^E2L * sC1 ----
  if constexpr (F::H2) {
    float l0[8], l1[8], l2[8], q[8];
#pragma unroll
    for (int u = 0; u < 8; ++u) {
      float4 v = fv[u];
      if constexpr (F::E2L > 0) powmul<F::E2L>(v, shiftrow(ML, u, cL));
      { float4 s1 = shiftrow(M1, u, c1); MUL4(v, s1); }
      l0[u] = v.x;
      l1[u] = fmaxf(l0[u], v.y);
      l2[u] = fmaxf(l1[u], v.z);
      q[u]  = fmaxf(l2[u], v.w);
    }
    SCAN8(q);
    float4 run = c2;
#pragma unroll
    for (int u = 0; u < 8; ++u) {
      float e = wshr1(q[u]);
      run.x = fmaxf(run.x, fmaxf(e, l0[u]));
      run.y = fmaxf(run.y, fmaxf(e, l1[u]));
      run.z = fmaxf(run.z, fmaxf(e, l2[u]));
      run.w = fmaxf(run.w, q[u]);
      M2[u] = run;
    }
  }

  // ---- pass 3: C3 = fv * sC2 ----
  if constexpr (F::H3) {
    float l0[8], l1[8], l2[8], q[8];
#pragma unroll
    for (int u = 0; u < 8; ++u) {
      float4 v = fv[u];
      { float4 s2 = shiftrow(M2, u, c2); MUL4(v, s2); }
      l0[u] = v.x;
      l1[u] = fmaxf(l0[u], v.y);
      l2[u] = fmaxf(l1[u], v.z);
      q[u]  = fmaxf(l2[u], v.w);
    }
    SCAN8(q);
    float4 run = c3;
#pragma unroll
    for (int u = 0; u < 8; ++u) {
      float e = wshr1(q[u]);
      run.x = fmaxf(run.x, fmaxf(e, l0[u]));
      run.y = fmaxf(run.y, fmaxf(e, l1[u]));
      run.z = fmaxf(run.z, fmaxf(e, l2[u]));
      run.w = fmaxf(run.w, q[u]);
      M3[u] = run;
    }
  }

  // ---- root pass: r(h) = fv * sL^RL * sC1^R1 * sC2^R2 * sC3^R3 ----
#pragma unroll
  for (int u = 0; u < 8; ++u) {
    float4 r = fv[u];
    if constexpr (F::RL > 0) powmul<F::RL>(r, shiftrow(ML, u, cL));
    if constexpr (F::R1 > 0) powmul<F::R1>(r, shiftrow(M1, u, c1));
    if constexpr (F::R2 > 0) powmul<F::R2>(r, shiftrow(M2, u, c2));
    if constexpr (F::R3 > 0) powmul<F::R3>(r, shiftrow(M3, u, c3));
    MAX4(racc, r);
  }

  // band carries (updated only after all uses of the old values)
  cL = ML[7];
  if constexpr (F::H1) c1 = M1[7];
  if constexpr (F::H2) c2 = M2[7];
  if constexpr (F::H3) c3 = M3[7];
}

// ---------------------------------------------------------------------------
// Band-parallel level-pass DP. One wave per (tree,b,c). Product space
// (exp isomorphism, verified R6-R10): f=(1+relu(x))*mask, sentinel 0.0,
// out = exp(asum)*m - 1.  Bands are processed in ping-pong pairs (NBAND
// even): band 2k computes from XA while prefetching into XB, band 2k+1 the
// reverse — no register-bank copy at band end.
// ---------------------------------------------------------------------------
template <int CL>
__device__ __forceinline__ void run_tree(const float* __restrict__ cp,
                                         float mask, float asum,
                                         float* __restrict__ outp, int lane) {
  const float4 z4 = make_float4(0.f, 0.f, 0.f, 0.f);
  float4 cL = z4, c1 = z4, c2 = z4, c3 = z4, racc = z4;

  float4 XA[8], XB[8];
#pragma unroll
  for (int u = 0; u < 8; ++u) XA[u] = *(const float4*)(cp + u * WW);

#pragma unroll 1
  for (int it = 0; it < NBAND; it += 2) {
    band_pass<CL>(cp, it,     mask, XA, XB, cL, c1, c2, c3, racc);
    band_pass<CL>(cp, it + 1, mask, XB, XA, cL, c1, c2, c3, racc);
  }

  float m = fmaxf(fmaxf(racc.x, racc.y), fmaxf(racc.z, racc.w));
#pragma unroll
  for (int d = 1; d < 64; d <<= 1) m = fmaxf(m, __shfl_xor(m, d));
  if (lane == 0) *outp = expf(asum) * m - 1.f;
}

// ---------------------------------------------------------------------------
// Block mapping (R12): I-cache + L2 aware.
// Under round-robin dispatch, blocks {c, c+256, c+512, c+768} are co-resident
// on one CU and blocks with equal (blk mod 8) land on the same XCD.
//   c = blk & 255 ; q = blk >> 8 ; t = c >> 5 ; bc = q*32 + (c & 31)
// gives: (1) all 4 co-resident blocks per CU share tree t -> ONE unrolled
// class body (~25 KB) in the 32 KB L1I instead of up to 4 distinct bodies
// (~100 KB thrash); (2) all 8 tree-blocks of a plane bc have blk ≡ bc&31 ≡
// bc (mod 8) -> same XCD -> plane read from its own L2.
// Pure index permutation: arithmetic per (t,b,c) task unchanged (bit-exact).
// ---------------------------------------------------------------------------
__global__ __launch_bounds__(64) void fis_kernel(const float* __restrict__ x,
                                                 const float* __restrict__ alphas,
                                                 float* __restrict__ out,
                                                 Cls cls) {
  const int lane = threadIdx.x;
  const int blk  = blockIdx.x;
  const int cg   = blk & 255;          // CU-group id (round-robin over 256 CUs)
  const int q    = blk >> 8;           // 0..3
  const int t    = cg >> 5;            // tree: constant per CU-group
  const int bc   = q * 32 + (cg & 31); // plane: 8 trees of a plane same XCD
  const int c    = bc & (CC - 1);
  const int b    = bc >> 4;

  const float* __restrict__ xp = x + (size_t)bc * (HH * WW);

  float asum = 0.f;
#pragma unroll
  for (int i = 0; i < NNODES; ++i) asum += alphas[(t * NNODES + i) * CC + c];

  const int   w0   = lane * 4;
  const float mask = (w0 < WW) ? 1.0f : 0.0f;
  const float* __restrict__ cp = xp + ((w0 < WW) ? w0 : (WW - 4));
  float* outp = out + ((size_t)b * NTREES + t) * CC + c;

  switch (cls.v[t]) {
    case 1: run_tree<1>(cp, mask, asum, outp, lane); break;
    case 2: run_tree<2>(cp, mask, asum, outp, lane); break;
    case 3: run_tree<3>(cp, mask, asum, outp, lane); break;
    case 4: run_tree<4>(cp, mask, asum, outp, lane); break;
    case 5: run_tree<5>(cp, mask, asum, outp, lane); break;
    case 6: run_tree<6>(cp, mask, asum, outp, lane); break;
    case 7: run_tree<7>(cp, mask, asum, outp, lane); break;
    case 8: run_tree<8>(cp, mask, asum, outp, lane); break;
    case 9: run_tree<9>(cp, mask, asum, outp, lane); break;
    default: break;
  }
}

extern "C" void kernel_launch(void* const* d_in, const int* in_sizes, int n_in,
                              void* d_out, int out_size, void* d_ws, size_t ws_size,
                              hipStream_t stream) {
  const float* x      = (const float*)d_in[0];
  const float* alphas = (const float*)d_in[1];
  float* out          = (float*)d_out;

  Forest f;
  nprng::make_forest(f);  // deterministic; same every call (graph-capture safe)

  Cls cls;
  for (int t = 0; t < NTREES; ++t)
    cls.v[t] = classify_tree(&f.par[t * NNODES]);

  dim3 grid(BB * CC * NTREES);  // 1024 single-wave blocks
  dim3 block(64);
  hipLaunchKernelGGL(fis_kernel, grid, block, 0, stream, x, alphas, out, cls);
}